// Round 1
// baseline (27495.465 us; speedup 1.0000x reference)
//
#include <hip/hip_runtime.h>
#include <math.h>

#define HD 1024
#define BB 50
#define SS 457
#define TT 32
#define VV 27
#define C3 3072

#define TC 64
#define LP 68   // padded LDS stride (floats), 16B-aligned rows, conflict-light

// ---------------------------------------------------------------------------
// Tiled f32 GEMM with K-split: out[z][ks][b][c] = sum_{k in split ks} A_z[b][k] * W_z[c][k]
// A rows are length K (contiguous). W is row-major (C, K). b in [0,50), padded to 64.
// grid: (C/64, nks, nz). If gatherZ1 && z==1, A row b = emb[tok[b]].
// ---------------------------------------------------------------------------
__global__ __launch_bounds__(256) void gemm_part_kernel(
    const float* __restrict__ A0, const float* __restrict__ W0,
    const float* __restrict__ A1, const float* __restrict__ W1,
    int K, int C, int nks, float* __restrict__ gpart,
    int gatherZ1, const int* __restrict__ tok, const float* __restrict__ emb)
{
  const int z = blockIdx.z;
  const float* A = z ? A1 : A0;
  const float* W = z ? W1 : W0;
  float* outp = gpart + (size_t)z * (size_t)nks * BB * C;
  const int kper = K / nks;
  const int k0 = blockIdx.y * kper;
  const int c0 = blockIdx.x * TC;

  __shared__ __align__(16) float As[16][LP];
  __shared__ __align__(16) float Ws[16][LP];

  const int tid = threadIdx.x;
  const int tx = tid & 15, ty = tid >> 4;
  float acc[4][4] = {{0.f}};

  for (int kk = 0; kk < kper; kk += 16) {
#pragma unroll
    for (int i = 0; i < 4; i++) {
      int e = tid + i * 256;
      int bb = e >> 4, kl = e & 15;
      float va = 0.f;
      if (bb < BB) {
        const float* arow;
        if (gatherZ1 && z == 1) arow = emb + (size_t)tok[bb] * HD;
        else                    arow = A + (size_t)bb * K;
        va = arow[k0 + kk + kl];
      }
      As[kl][bb] = va;
      int cc = c0 + bb;
      Ws[kl][bb] = W[(size_t)cc * K + k0 + kk + kl];
    }
    __syncthreads();
#pragma unroll
    for (int kl = 0; kl < 16; kl++) {
      const float4 a4 = *(const float4*)&As[kl][ty << 2];
      const float4 w4 = *(const float4*)&Ws[kl][tx << 2];
      float av[4] = {a4.x, a4.y, a4.z, a4.w};
      float wv[4] = {w4.x, w4.y, w4.z, w4.w};
#pragma unroll
      for (int i = 0; i < 4; i++)
#pragma unroll
        for (int j = 0; j < 4; j++)
          acc[i][j] += av[i] * wv[j];
    }
    __syncthreads();
  }

#pragma unroll
  for (int i = 0; i < 4; i++) {
    int b = (ty << 2) + i;
    if (b >= BB) continue;
    float* orow = outp + ((size_t)blockIdx.y * BB + b) * C + c0 + (tx << 2);
#pragma unroll
    for (int j = 0; j < 4; j++) orow[j] = acc[i][j];
  }
}

// ---------------------------------------------------------------------------
// GRU gate update: reads partial sums (gh from gpart[0], gi from gpart[1] or
// computed inline from the 3-dim encoder layer-0 input), applies PyTorch GRU
// gate math, writes h (and optionally a strided copy for enc_outs / comb).
// ---------------------------------------------------------------------------
__global__ __launch_bounds__(256) void gru_gate_kernel(
    const float* __restrict__ gpart, int C, int nks, int ihFromPart,
    const float* __restrict__ Wih0, const float* __restrict__ x, int t,
    const float* __restrict__ bih, const float* __restrict__ bhh,
    float* __restrict__ h, float* __restrict__ seq_out, int seq_stride)
{
  int tid = blockIdx.x * 256 + threadIdx.x;
  if (tid >= BB * HD) return;
  int b = tid >> 10, j = tid & 1023;

  float ghr = 0.f, ghz = 0.f, ghn = 0.f;
  for (int ks = 0; ks < nks; ks++) {
    const float* row = gpart + ((size_t)ks * BB + b) * C;
    ghr += row[j]; ghz += row[HD + j]; ghn += row[2 * HD + j];
  }
  float gir = 0.f, giz = 0.f, gin = 0.f;
  if (ihFromPart) {
    const float* g1 = gpart + (size_t)nks * BB * C;
    for (int ks = 0; ks < nks; ks++) {
      const float* row = g1 + ((size_t)ks * BB + b) * C;
      gir += row[j]; giz += row[HD + j]; gin += row[2 * HD + j];
    }
  } else {
    float x0 = x[(size_t)b * 2 * SS + t];
    float x1 = x[(size_t)b * 2 * SS + SS + t];
    float pp = (float)t;
    const float* wr = Wih0 + (size_t)j * 3;
    const float* wz = Wih0 + (size_t)(HD + j) * 3;
    const float* wn = Wih0 + (size_t)(2 * HD + j) * 3;
    gir = wr[0] * x0 + wr[1] * x1 + wr[2] * pp;
    giz = wz[0] * x0 + wz[1] * x1 + wz[2] * pp;
    gin = wn[0] * x0 + wn[1] * x1 + wn[2] * pp;
  }
  gir += bih[j];      giz += bih[HD + j];      gin += bih[2 * HD + j];
  ghr += bhh[j];      ghz += bhh[HD + j];      ghn += bhh[2 * HD + j];

  float r  = 1.f / (1.f + expf(-(gir + ghr)));
  float zg = 1.f / (1.f + expf(-(giz + ghz)));
  float n  = tanhf(gin + r * ghn);
  float hv = h[tid];
  float hn2 = (1.f - zg) * n + zg * hv;
  h[tid] = hn2;
  if (seq_out) seq_out[(size_t)b * seq_stride + j] = hn2;
}

// ---------------------------------------------------------------------------
// score[b][s] = dot(enc[s][b][:], q[b][:]) ; one wave per (b,s)
// ---------------------------------------------------------------------------
__global__ __launch_bounds__(256) void score_kernel(
    const float* __restrict__ enc, const float* __restrict__ q,
    float* __restrict__ sc)
{
  int gw = (blockIdx.x * 256 + threadIdx.x) >> 6;
  int lane = threadIdx.x & 63;
  if (gw >= BB * SS) return;
  int b = gw / SS, s = gw - b * SS;
  const float* e = enc + ((size_t)s * BB + b) * HD;
  const float* qq = q + (size_t)b * HD;
  float acc = 0.f;
#pragma unroll
  for (int i = 0; i < 16; i++) acc += e[lane + 64 * i] * qq[lane + 64 * i];
  for (int off = 32; off; off >>= 1) acc += __shfl_down(acc, off);
  if (lane == 0) sc[b * SS + s] = acc;
}

// ---------------------------------------------------------------------------
// softmax over s (457) per batch row; writes normalized weights and the
// attn_w output slice [b][s][t].
// ---------------------------------------------------------------------------
__global__ __launch_bounds__(512) void softmax_attn_kernel(
    const float* __restrict__ sc, float* __restrict__ w,
    float* __restrict__ attn_out, int t)
{
  int b = blockIdx.x;
  __shared__ float red[512];
  float m = -1e30f;
  for (int s = threadIdx.x; s < SS; s += 512) m = fmaxf(m, sc[b * SS + s]);
  red[threadIdx.x] = m; __syncthreads();
  for (int o = 256; o; o >>= 1) {
    if (threadIdx.x < o) red[threadIdx.x] = fmaxf(red[threadIdx.x], red[threadIdx.x + o]);
    __syncthreads();
  }
  m = red[0]; __syncthreads();
  float sum = 0.f;
  for (int s = threadIdx.x; s < SS; s += 512) sum += expf(sc[b * SS + s] - m);
  red[threadIdx.x] = sum; __syncthreads();
  for (int o = 256; o; o >>= 1) {
    if (threadIdx.x < o) red[threadIdx.x] += red[threadIdx.x + o];
    __syncthreads();
  }
  float inv = 1.f / red[0];
  for (int s = threadIdx.x; s < SS; s += 512) {
    float v = expf(sc[b * SS + s] - m) * inv;
    w[b * SS + s] = v;
    attn_out[((size_t)b * SS + s) * TT + t] = v;
  }
}

// ---------------------------------------------------------------------------
// a[b][j] = sum_s w[b][s]*enc[s][b][j]  -> comb[b][1024+j]
// ---------------------------------------------------------------------------
__global__ __launch_bounds__(256) void amix_kernel(
    const float* __restrict__ enc, const float* __restrict__ w,
    float* __restrict__ comb)
{
  int tid = blockIdx.x * 256 + threadIdx.x;
  if (tid >= BB * HD) return;
  int b = tid >> 10, j = tid & 1023;
  const float* wb = w + b * SS;
  float acc = 0.f;
#pragma unroll 4
  for (int s = 0; s < SS; s++) acc += wb[s] * enc[((size_t)s * BB + b) * HD + j];
  comb[(size_t)b * 2048 + HD + j] = acc;
}

// hfc[b][i] = relu(sum_ks gpart[ks][b][i] + bias[i])
__global__ __launch_bounds__(256) void fcrelu_kernel(
    const float* __restrict__ gpart, int nks,
    const float* __restrict__ bias, float* __restrict__ hfc)
{
  int tid = blockIdx.x * 256 + threadIdx.x;
  if (tid >= BB * HD) return;
  int b = tid >> 10, i = tid & 1023;
  float acc = bias[i];
  for (int ks = 0; ks < nks; ks++) acc += gpart[((size_t)ks * BB + b) * HD + i];
  hfc[tid] = fmaxf(acc, 0.f);
}

// logits[b][v] = dot(hfc[b], fcW[v]) + fcb[v] ; one wave per (b,v); writes d_out
__global__ __launch_bounds__(256) void logits_kernel(
    const float* __restrict__ hfc, const float* __restrict__ fcW,
    const float* __restrict__ fcb, float* __restrict__ outv, int t)
{
  int gw = (blockIdx.x * 256 + threadIdx.x) >> 6;
  int lane = threadIdx.x & 63;
  if (gw >= BB * VV) return;
  int b = gw / VV, v = gw - b * VV;
  const float* hb = hfc + (size_t)b * HD;
  const float* wv = fcW + (size_t)v * HD;
  float acc = 0.f;
#pragma unroll
  for (int i = 0; i < 16; i++) acc += hb[lane + 64 * i] * wv[lane + 64 * i];
  for (int off = 32; off; off >>= 1) acc += __shfl_down(acc, off);
  if (lane == 0) outv[((size_t)b * TT + t) * VV + v] = acc + fcb[v];
}

// tok[b] = argmax_v logits[b][t][v]  (first max, like jnp.argmax)
__global__ __launch_bounds__(64) void argmax_kernel(
    const float* __restrict__ outv, int t, int* __restrict__ tok)
{
  int b = threadIdx.x;
  if (b >= BB) return;
  const float* l = outv + ((size_t)b * TT + t) * VV;
  float best = l[0]; int bi = 0;
  for (int v = 1; v < VV; v++) { float xv = l[v]; if (xv > best) { best = xv; bi = v; } }
  tok[b] = bi;
}

__global__ __launch_bounds__(256) void init_kernel(
    float* __restrict__ h0, float* __restrict__ h1, int* __restrict__ tok)
{
  int tid = blockIdx.x * 256 + threadIdx.x;
  if (tid < BB * HD) { h0[tid] = 0.f; h1[tid] = 0.f; }
  if (tid < BB) tok[tid] = 0;
}

__global__ __launch_bounds__(256) void hidcopy_kernel(
    const float* __restrict__ h0, const float* __restrict__ h1,
    float* __restrict__ outh)
{
  int tid = blockIdx.x * 256 + threadIdx.x;
  if (tid >= BB * HD) return;
  outh[tid] = h0[tid];
  outh[BB * HD + tid] = h1[tid];
}

// ---------------------------------------------------------------------------
extern "C" void kernel_launch(void* const* d_in, const int* in_sizes, int n_in,
                              void* d_out, int out_size, void* d_ws, size_t ws_size,
                              hipStream_t stream)
{
  const float* x     = (const float*)d_in[0];
  const float* emb   = (const float*)d_in[1];
  const float* eWih0 = (const float*)d_in[2];
  const float* eWhh0 = (const float*)d_in[3];
  const float* ebih0 = (const float*)d_in[4];
  const float* ebhh0 = (const float*)d_in[5];
  const float* eWih1 = (const float*)d_in[6];
  const float* eWhh1 = (const float*)d_in[7];
  const float* ebih1 = (const float*)d_in[8];
  const float* ebhh1 = (const float*)d_in[9];
  const float* dWih  = (const float*)d_in[10];
  const float* dWhh  = (const float*)d_in[11];
  const float* dbih  = (const float*)d_in[12];
  const float* dbhh  = (const float*)d_in[13];
  const float* attnW = (const float*)d_in[14];
  const float* attnB = (const float*)d_in[15];
  const float* fcW   = (const float*)d_in[16];
  const float* fcB   = (const float*)d_in[17];
  float* out = (float*)d_out;

  float* ws     = (float*)d_ws;
  float* h0     = ws;
  float* h1     = h0 + BB * HD;
  float* gpart  = h1 + BB * HD;                 // 16*50*3072 floats
  float* enc    = gpart + 16 * BB * C3;         // 457*50*1024 floats
  float* comb   = enc + (size_t)SS * BB * HD;   // 50*2048
  float* scoreb = comb + BB * 2048;             // 50*457
  float* wsm    = scoreb + BB * SS;             // 50*457
  float* hfc    = wsm + BB * SS;                // 50*1024
  int*   tok    = (int*)(hfc + BB * HD);

  float* out_vec  = out;                        // (B,T,V)  43200
  float* out_hid  = out + BB * TT * VV;         // (2,B,H)  102400
  float* out_attn = out_hid + 2 * BB * HD;      // (B,S,T)  731200

  init_kernel<<<200, 256, 0, stream>>>(h0, h1, tok);

  // -------- encoder: interleave layer0/layer1 per timestep --------
  for (int t = 0; t < SS; t++) {
    gemm_part_kernel<<<dim3(C3 / TC, 16, 1), 256, 0, stream>>>(
        h0, eWhh0, nullptr, nullptr, HD, C3, 16, gpart, 0, nullptr, nullptr);
    gru_gate_kernel<<<200, 256, 0, stream>>>(
        gpart, C3, 16, 0, eWih0, x, t, ebih0, ebhh0, h0, nullptr, 0);
    gemm_part_kernel<<<dim3(C3 / TC, 8, 2), 256, 0, stream>>>(
        h1, eWhh1, h0, eWih1, HD, C3, 8, gpart, 0, nullptr, nullptr);
    gru_gate_kernel<<<200, 256, 0, stream>>>(
        gpart, C3, 8, 1, nullptr, nullptr, 0, ebih1, ebhh1, h1,
        enc + (size_t)t * BB * HD, HD);
  }

  // -------- decoder: T autoregressive steps --------
  for (int t = 0; t < TT; t++) {
    gemm_part_kernel<<<dim3(C3 / TC, 8, 2), 256, 0, stream>>>(
        h0, dWhh, nullptr, dWih, HD, C3, 8, gpart, 1, tok, emb);
    gru_gate_kernel<<<200, 256, 0, stream>>>(
        gpart, C3, 8, 1, nullptr, nullptr, 0, dbih, dbhh, h0, nullptr, 0);
    gemm_part_kernel<<<dim3(C3 / TC, 8, 2), 256, 0, stream>>>(
        h1, dWhh + (size_t)C3 * HD, h0, dWih + (size_t)C3 * HD,
        HD, C3, 8, gpart, 0, nullptr, nullptr);
    gru_gate_kernel<<<200, 256, 0, stream>>>(
        gpart, C3, 8, 1, nullptr, nullptr, 0, dbih + C3, dbhh + C3, h1,
        comb, 2048);

    score_kernel<<<(BB * SS * 64 + 255) / 256, 256, 0, stream>>>(enc, h1, scoreb);
    softmax_attn_kernel<<<BB, 512, 0, stream>>>(scoreb, wsm, out_attn, t);
    amix_kernel<<<200, 256, 0, stream>>>(enc, wsm, comb);

    gemm_part_kernel<<<dim3(HD / TC, 16, 1), 256, 0, stream>>>(
        comb, attnW, nullptr, nullptr, 2 * HD, HD, 16, gpart, 0, nullptr, nullptr);
    fcrelu_kernel<<<200, 256, 0, stream>>>(gpart, 16, attnB, hfc);
    logits_kernel<<<(BB * VV * 64 + 255) / 256, 256, 0, stream>>>(
        hfc, fcW, fcB, out_vec, t);
    argmax_kernel<<<1, 64, 0, stream>>>(out_vec, t, tok);
  }

  hidcopy_kernel<<<200, 256, 0, stream>>>(h0, h1, out_hid);
}